// Round 20
// baseline (114.504 us; speedup 1.0000x reference)
//
#include <hip/hip_runtime.h>
#include <hip/hip_bf16.h>

typedef unsigned short u16;
typedef unsigned int   u32;
typedef __attribute__((ext_vector_type(8)))  __bf16 bf16x8;
typedef __attribute__((ext_vector_type(4)))  float  f32x4;
typedef __attribute__((ext_vector_type(16))) float  f32x16;
typedef __attribute__((ext_vector_type(4)))  float  float4_t;
typedef __attribute__((ext_vector_type(8)))  u16    u16x8;
typedef __attribute__((ext_vector_type(4)))  u16    u16x4;
typedef __attribute__((ext_vector_type(4)))  u32    u32x4;

#define DEV static __device__ __forceinline__

// ---- helpers --------------------------------------------------------------

DEV u16 f2b(float f) {                 // f32 -> bf16 (RNE), data is finite
  u32 u = __builtin_bit_cast(u32, f);
  u32 r = u + 0x7FFFu + ((u >> 16) & 1u);
  return (u16)(r >> 16);
}

DEV u32 cvtpk(float lo, float hi) {    // pack 2 f32 -> 2 bf16 in one u32 (RNE)
  u32 r;
  asm("v_cvt_pk_bf16_f32 %0, %1, %2" : "=v"(r) : "v"(lo), "v"(hi));
  return r;
}

// bare v_exp_f32 (inputs bounded; no OCML wrapper -- R11 verified -14 us).
DEV float fexp2(float x) { return __builtin_amdgcn_exp2f(x); }

// BURIED: v_permlane32_swap_b32 (R5+R10); HBM-partial split-KV (R8); register
// squeezes (R12/R14); aligned-pack attn (R17/R18: VGPR 68/72 > 64 cliff).
// INVARIANTS: (1) attn must allocate <= 64 VGPR -- R16/R19 source does;
// (2) never launch_bounds below a kernel's natural VGPR need;
// (3) more waves/CU at CONSTANT register fit is the proven latency cure
//     (R16 attn: 8->16 waves/CU = -9%). This round applies (3) to gemm_qkv.

DEV bf16x8 ldfrag(const u16* p) {      // 16B LDS vector load -> mfma operand
  u16x8 t = *(const u16x8*)p;
  return __builtin_bit_cast(bf16x8, t);
}

DEV void gload16(void* lds, const void* g) {
  // async global->LDS, 16B/lane. LDS dest = wave-uniform base + lane*16.
  __builtin_amdgcn_global_load_lds(
      (const __attribute__((address_space(1))) void*)g,
      (__attribute__((address_space(3))) void*)lds, 16, 0, 0);
}

// XOR bank swizzles (u16 offset for logical (row, col16); XOR is an involution)
DEV int swz8(int row, int col16)  { return row * 64  + ((col16 ^ (row & 7))  << 3); } // 128B rows
DEV int swz16(int row, int col16) { return row * 128 + ((col16 ^ (row & 15)) << 3); } // 256B rows

// ---- fused cast f32 -> bf16: x (4096x1024) + 4 weight matrices, one launch --

__global__ void cast_all(const float* __restrict__ x,
                         const float* __restrict__ s0, const float* __restrict__ s1,
                         const float* __restrict__ s2, const float* __restrict__ s3,
                         u16* __restrict__ xb,
                         u16* __restrict__ d0, u16* __restrict__ d1,
                         u16* __restrict__ d2, u16* __restrict__ d3) {
  const int gid = blockIdx.x * 256 + threadIdx.x;   // 4096 blocks x 256 = 1,048,576
  const float* src; u16* dst; int i;
  if (gid < 524288) { src = x; dst = xb; i = gid; }
  else {
    const int g = gid - 524288, which = g >> 17;    // 131072 vec8 per matrix
    i = g & 131071;
    src = which == 0 ? s0 : which == 1 ? s1 : which == 2 ? s2 : s3;
    dst = which == 0 ? d0 : which == 1 ? d1 : which == 2 ? d2 : d3;
  }
  float4_t a = ((const float4_t*)src)[2 * i];
  float4_t b = ((const float4_t*)src)[2 * i + 1];
  u16x8 o;
  o[0] = f2b(a[0]); o[1] = f2b(a[1]); o[2] = f2b(a[2]); o[3] = f2b(a[3]);
  o[4] = f2b(b[0]); o[5] = f2b(b[1]); o[6] = f2b(b[2]); o[7] = f2b(b[3]);
  ((u16x8*)dst)[i] = o;
}

// ---- QKV GEMM: C = A @ B^T, A[4096][1024]=x, B[3072][1024]=Wq|Wk|Wv.
// 128x128 tile, grid 32x24=768. NEW (R20): 512-thread blocks -- 8 waves each
// computing a 64x32 sub-tile (acc 16 f32/lane). Same tile/LDS (32 KB), but
// waves/CU rises 12 -> 16-32 (latency hiding; gemm_qkv was 70% both-pipes-idle
// at 12 waves/CU). (512,4) caps VGPR at 128 -- need ~60, no squeeze.
// T2 XOR-swizzle on As/Bs (R15 win); V packed 8B stores (R18 win).

__global__ __launch_bounds__(512, 4) void gemm_qkv(
    const u16* __restrict__ A, const u16* __restrict__ Bm,
    const float* __restrict__ bq, const float* __restrict__ bk, const float* __restrict__ bv,
    u16* __restrict__ oQ, u16* __restrict__ oK, u16* __restrict__ oV)
{
  __shared__ u16 As[128 * 64];
  __shared__ u16 Bs[128 * 64];
  const int t = threadIdx.x, w = t >> 6, ln = t & 63;
  const int bm = blockIdx.x & 31, bn = blockIdx.x >> 5;
  const int m0 = bm * 128, n0 = bn * 128;
  const int wm = (w >> 2) * 64, wn = (w & 3) * 32;   // 2M x 4N wave grid
  const int srow = ln >> 3;
  const int scolx = ((ln & 7) ^ (ln >> 3)) << 3;   // pre-swizzled source col (u16)

  f32x4 acc[4][2] = {};

  for (int k0 = 0; k0 < 1024; k0 += 64) {
#pragma unroll
    for (int i = 0; i < 2; ++i) {
      const int c = w * 2 + i;                     // chunks 0..15 (8 rows each)
      gload16(&As[c * 512], A  + (size_t)(m0 + c * 8 + srow) * 1024 + k0 + scolx);
      gload16(&Bs[c * 512], Bm + (size_t)(n0 + c * 8 + srow) * 1024 + k0 + scolx);
    }
    __syncthreads();
#pragma unroll
    for (int kh = 0; kh < 2; ++kh) {
      bf16x8 af[4], bf[2];
#pragma unroll
      for (int i = 0; i < 4; ++i)
        af[i] = ldfrag(&As[swz8(wm + i * 16 + (ln & 15), kh * 4 + (ln >> 4))]);
#pragma unroll
      for (int j = 0; j < 2; ++j)
        bf[j] = ldfrag(&Bs[swz8(wn + j * 16 + (ln & 15), kh * 4 + (ln >> 4))]);
#pragma unroll
      for (int i = 0; i < 4; ++i)
#pragma unroll
        for (int j = 0; j < 2; ++j)
          acc[i][j] = __builtin_amdgcn_mfma_f32_16x16x32_bf16(af[i], bf[j], acc[i][j], 0, 0, 0);
    }
    __syncthreads();
  }

  // epilogue: D mapping col=lane&15, row=(lane>>4)*4+reg  [verified m89/m91]
#pragma unroll
  for (int i = 0; i < 4; ++i) {
#pragma unroll
    for (int j = 0; j < 2; ++j) {
      const int col = n0 + wn + j * 16 + (ln & 15);
      const int p = col >> 10, nn = col & 1023;         // uniform per block
      const int h = nn >> 6, d = nn & 63;
      if (p == 2) {
        // V: lane owns 4 consecutive s for fixed d -> one packed 8B store
        const int row0 = m0 + wm + i * 16 + (ln >> 4) * 4;
        const int b = row0 >> 11, sv = row0 & 2047;
        u16x4 pk;
#pragma unroll
        for (int r = 0; r < 4; ++r) pk[r] = f2b(acc[i][j][r] + bv[nn]);
        *(u16x4*)&oV[((size_t)((b * 16 + h) * 64 + d) << 11) + sv] = pk;
      } else {
#pragma unroll
        for (int r = 0; r < 4; ++r) {
          const int row = m0 + wm + i * 16 + (ln >> 4) * 4 + r;
          const int b = row >> 11, s = row & 2047;
          const float v = acc[i][j][r];
          const size_t qk = ((size_t)((b * 16 + h) * 2048 + s) << 6) + d;
          if (p == 0) oQ[qk] = f2b((v + bq[nn]) * 0.18033688f);  // 1/8 * log2(e)
          else        oK[qk] = f2b(v + bk[nn]);
        }
      }
    }
  }
}

// ---- output GEMM: out = ctx @ Wo^T + bo, f32 out. 128x64 tile, grid 512. ----

__global__ __launch_bounds__(256, 2) void gemm_o(
    const u16* __restrict__ A, const u16* __restrict__ Bm,
    const float* __restrict__ bias, float* __restrict__ oF)
{
  __shared__ u16 As[128 * 64];
  __shared__ u16 Bs[64 * 64];
  const int t = threadIdx.x, w = t >> 6, ln = t & 63;
  const int bm = blockIdx.x & 31, bn = blockIdx.x >> 5;   // 32 x 16
  const int m0 = bm * 128, n0 = bn * 64;
  const int wm = (w >> 1) * 64, wn = (w & 1) * 32;
  const int srow = ln >> 3;
  const int scolx = ((ln & 7) ^ (ln >> 3)) << 3;   // pre-swizzled source col (u16)

  f32x4 acc[4][2] = {};

  for (int k0 = 0; k0 < 1024; k0 += 64) {
#pragma unroll
    for (int i = 0; i < 4; ++i) {
      const int c = w * 4 + i;                     // A chunks 0..15
      gload16(&As[c * 512], A + (size_t)(m0 + c * 8 + srow) * 1024 + k0 + scolx);
    }
#pragma unroll
    for (int i = 0; i < 2; ++i) {
      const int c = w * 2 + i;                     // B chunks 0..7
      gload16(&Bs[c * 512], Bm + (size_t)(n0 + c * 8 + srow) * 1024 + k0 + scolx);
    }
    __syncthreads();
#pragma unroll
    for (int kh = 0; kh < 2; ++kh) {
      bf16x8 af[4], bf[2];
#pragma unroll
      for (int i = 0; i < 4; ++i)
        af[i] = ldfrag(&As[swz8(wm + i * 16 + (ln & 15), kh * 4 + (ln >> 4))]);
#pragma unroll
      for (int j = 0; j < 2; ++j)
        bf[j] = ldfrag(&Bs[swz8(wn + j * 16 + (ln & 15), kh * 4 + (ln >> 4))]);
#pragma unroll
      for (int i = 0; i < 4; ++i)
#pragma unroll
        for (int j = 0; j < 2; ++j)
          acc[i][j] = __builtin_amdgcn_mfma_f32_16x16x32_bf16(af[i], bf[j], acc[i][j], 0, 0, 0);
    }
    __syncthreads();
  }

#pragma unroll
  for (int i = 0; i < 4; ++i) {
#pragma unroll
    for (int j = 0; j < 2; ++j) {
      const int col = n0 + wn + j * 16 + (ln & 15);
#pragma unroll
      for (int r = 0; r < 4; ++r) {
        const int row = m0 + wm + i * 16 + (ln >> 4) * 4 + r;
        oF[(size_t)row * 1024 + col] = acc[i][j][r] + bias[col];
      }
    }
  }
}

// ---- flash attention: R16/R19 VERBATIM (47.5 us, 64 VGPR, 35% occupancy) ----
// 512 thr = 8 waves (qgrp=w&3 x g=w>>2 kv half), dbuf KV, issue-first
// prefetch, XCD-local bh, max-free softmax, (512,2), cross-hi exchange via
// shfl_xor+cndmask (verified R4/R6), LDS combine of the two kv halves.

__global__ __launch_bounds__(512, 2) void attn_kernel(
    const u16* __restrict__ Qg, const u16* __restrict__ Kg,
    const u16* __restrict__ Vtg, u16* __restrict__ Ctx)
{
  __shared__ u16 Kb[2][128 * 64];  // K tiles (Q staged in Kb[1] once); swz8
  __shared__ u16 Vb[2][64 * 128];  // V^T tiles [d][kv]; swz16

  const int t = threadIdx.x, w = t >> 6, ln = t & 63;
  const int lo5 = ln & 31, hi = ln >> 5;
  const int qgrp = w & 3;          // 32-q-row group within the 128-row block
  const int g = w >> 2;            // kv half of each 128-tile (0: [0,64), 1: [64,128))
  const int bh = blockIdx.x & 31;           // 0..31 = b*16+h (same-head -> same XCD)
  const int q0 = (blockIdx.x >> 5) * 128;
  const size_t base = (size_t)bh << 17;     // bh*2048*64

  auto stageKV = [&](int buf, int kv0) {
#pragma unroll
    for (int i = 0; i < 2; ++i) {
      const int c = w * 2 + i;               // chunks 0..15 across 8 waves
      gload16(&Kb[buf][c * 512],
              Kg + base + (size_t)(kv0 + c * 8 + (ln >> 3)) * 64 + (((ln & 7) ^ (ln >> 3)) << 3));
      const int vr = c * 4 + (ln >> 4);      // V^T row (d)
      gload16(&Vb[buf][c * 512],
              Vtg + base + (size_t)vr * 2048 + kv0 + (((ln & 15) ^ (vr & 15)) << 3));
    }
  };

  // stage Q tile [128][64] into Kb[1] (pre-swizzled source, linear LDS dest)
#pragma unroll
  for (int i = 0; i < 2; ++i) {
    const int c = w * 2 + i;
    gload16(&Kb[1][c * 512],
            Qg + base + (size_t)(q0 + c * 8 + (ln >> 3)) * 64 + (((ln & 7) ^ (ln >> 3)) << 3));
  }
  __syncthreads();

  stageKV(0, 0);                   // K0/V0 in flight while we read Q fragments

  // Q B-fragments: col=q=lo5, k(d) = kh*16 + hi*8 + j
  bf16x8 qf[4];
#pragma unroll
  for (int kh = 0; kh < 4; ++kh)
    qf[kh] = ldfrag(&Kb[1][swz8(qgrp * 32 + lo5, 2 * kh + hi)]);
  __syncthreads();                 // drains K0/V0; all waves read Q before kt=0 hits Kb[1]

  f32x16 acc[2] = {};              // O[q][d]: db=0,1; row=(rg&3)+8*(rg>>2)+4*hi, col=db*32+lo5
  float l_i = 0.f;                 // softmax denominator for this wave's kv half

#pragma unroll 2
  for (int kt = 0; kt < 16; ++kt) {
    const int cur = kt & 1;
    if (kt < 15) stageKV(cur ^ 1, (kt + 1) * 128);   // issue-first prefetch
    const u16* KQs = Kb[cur];
    const u16* Vs  = Vb[cur];

    // ---- S^T = K Q^T over this wave's 64-kv half (g)
    f32x16 S0 = {}, S1 = {};
    __builtin_amdgcn_s_setprio(1);
#pragma unroll
    for (int kh = 0; kh < 4; ++kh) {
      bf16x8 a0 = ldfrag(&KQs[swz8(g * 64 + lo5,      2 * kh + hi)]);
      bf16x8 a1 = ldfrag(&KQs[swz8(g * 64 + 32 + lo5, 2 * kh + hi)]);
      S0 = __builtin_amdgcn_mfma_f32_32x32x16_bf16(a0, qf[kh], S0, 0, 0, 0);
      S1 = __builtin_amdgcn_mfma_f32_32x32x16_bf16(a1, qf[kh], S1, 0, 0, 0);
    }
    __builtin_amdgcn_s_setprio(0);

    // ---- P = exp2(S) directly (max-free), row sum via 4 partial accumulators
    float s0 = 0.f, s1 = 0.f, s2 = 0.f, s3 = 0.f;
#pragma unroll
    for (int r = 0; r < 16; r += 4) {
      S0[r]     = fexp2(S0[r]);     s0 += S0[r];
      S0[r + 1] = fexp2(S0[r + 1]); s1 += S0[r + 1];
      S0[r + 2] = fexp2(S0[r + 2]); s2 += S0[r + 2];
      S0[r + 3] = fexp2(S0[r + 3]); s3 += S0[r + 3];
    }
#pragma unroll
    for (int r = 0; r < 16; r += 4) {
      S1[r]     = fexp2(S1[r]);     s0 += S1[r];
      S1[r + 1] = fexp2(S1[r + 1]); s1 += S1[r + 1];
      S1[r + 2] = fexp2(S1[r + 2]); s2 += S1[r + 2];
      S1[r + 3] = fexp2(S1[r + 3]); s3 += S1[r + 3];
    }
    float sum = (s0 + s1) + (s2 + s3);
    sum += __shfl_xor(sum, 32);
    l_i += sum;

    // ---- pack P -> u32 words per kv-4-block (own parity blocks n = 2u + hi)
    u32 w2[8][2];
#pragma unroll
    for (int u = 0; u < 8; ++u) {
      const int tt = u & 3;
      if (u < 4) {
        w2[u][0] = cvtpk(S0[4 * tt + 0], S0[4 * tt + 1]);
        w2[u][1] = cvtpk(S0[4 * tt + 2], S0[4 * tt + 3]);
      } else {
        w2[u][0] = cvtpk(S1[4 * tt + 0], S1[4 * tt + 1]);
        w2[u][1] = cvtpk(S1[4 * tt + 2], S1[4 * tt + 3]);
      }
    }

    // ---- PV: A-frag pa[m] = P[q][kv=16m+8hi+j]; exchange odd/even blocks across hi.
    // All w2 indices STATIC; hi-dependent selection via v_cndmask on values.
    __builtin_amdgcn_s_setprio(1);
#pragma unroll
    for (int m = 0; m < 4; ++m) {
      const u32 a0 = w2[2 * m][0],     a1 = w2[2 * m][1];      // even-parity block
      const u32 b0 = w2[2 * m + 1][0], b1 = w2[2 * m + 1][1];  // odd-parity block
      const u32 o0 = hi ? b0 : a0,     o1 = hi ? b1 : a1;      // own block
      const u32 x0 = hi ? a0 : b0,     x1 = hi ? a1 : b1;      // sent to partner
      const u32 r0 = (u32)__shfl_xor((int)x0, 32);
      const u32 r1 = (u32)__shfl_xor((int)x1, 32);
      u32x4 fw;
      fw[0] = hi ? r0 : o0;   // block 4m+2hi   (kv 16m+8hi .. +3)
      fw[1] = hi ? r1 : o1;
      fw[2] = hi ? o0 : r0;   // block 4m+2hi+1 (kv 16m+8hi+4 .. +7)
      fw[3] = hi ? o1 : r1;
      const bf16x8 pa = __builtin_bit_cast(bf16x8, fw);
      const bf16x8 v0 = ldfrag(&Vs[swz16(lo5,      g * 8 + 2 * m + hi)]);
      const bf16x8 v1 = ldfrag(&Vs[swz16(32 + lo5, g * 8 + 2 * m + hi)]);
      acc[0] = __builtin_amdgcn_mfma_f32_32x32x16_bf16(pa, v0, acc[0], 0, 0, 0);
      acc[1] = __builtin_amdgcn_mfma_f32_32x32x16_bf16(pa, v1, acc[1], 0, 0, 0);
    }
    __builtin_amdgcn_s_setprio(0);

    __syncthreads();   // drains stage(kt+1); LDS handoff for next tile
  }

  // ---- combine the two kv halves (max-free: plain adds), reuse Kb/Vb as f32
  float* Lo  = (float*)&Kb[0][0];          // [4 qgrp][32 row][64 col] f32 = 32 KB
  float* Lml = (float*)&Vb[0][0];          // [4 qgrp][32 q] l partials (512 B)
  if (g == 1) {
    if (hi == 0) Lml[qgrp * 32 + lo5] = l_i;
#pragma unroll
    for (int rg = 0; rg < 16; ++rg) {
      const int row = (rg & 3) + 8 * (rg >> 2) + 4 * hi;
#pragma unroll
      for (int db = 0; db < 2; ++db)
        Lo[(qgrp * 32 + row) * 64 + db * 32 + lo5] = acc[db][rg];
    }
  }
  __syncthreads();

  if (g == 0) {                            // merge + normalize + write ctx
    const float linv = 1.f / (l_i + Lml[qgrp * 32 + lo5]);
    const int b = bh >> 4, h = bh & 15;
#pragma unroll
    for (int rg = 0; rg < 16; ++rg) {
      const int qrow = (rg & 3) + 8 * (rg >> 2) + 4 * hi;
      const float li = __shfl(linv, qrow);
      const int s = q0 + qgrp * 32 + qrow;
#pragma unroll
      for (int db = 0; db < 2; ++db) {
        const int d = db * 32 + lo5;
        const float oB = Lo[(qgrp * 32 + qrow) * 64 + d];
        Ctx[((size_t)(b * 2048 + s) << 10) + h * 64 + d] = f2b((acc[db][rg] + oB) * li);
      }
    }
  }
}

// ---- launch ----------------------------------------------------------------

extern "C" void kernel_launch(void* const* d_in, const int* in_sizes, int n_in,
                              void* d_out, int out_size, void* d_ws, size_t ws_size,
                              hipStream_t stream) {
  const float* x  = (const float*)d_in[0];
  const float* Wq = (const float*)d_in[2];
  const float* bq = (const float*)d_in[3];
  const float* Wk = (const float*)d_in[4];
  const float* bk = (const float*)d_in[5];
  const float* Wv = (const float*)d_in[6];
  const float* bv = (const float*)d_in[7];
  const float* Wo = (const float*)d_in[8];
  const float* bo = (const float*)d_in[9];

  char* ws = (char*)d_ws;
  // workspace layout (48 MB total), all offsets 2MB-aligned
  u16* xb  = (u16*)(ws);                        // x bf16 [4096][1024]
  u16* wq  = (u16*)(ws + (8ull  << 20));        // Wq|Wk|Wv contiguous [3072][1024]
  u16* wk  = (u16*)(ws + (10ull << 20));
  u16* wv  = (u16*)(ws + (12ull << 20));
  u16* wo  = (u16*)(ws + (14ull << 20));        // Wo [1024][1024]
  u16* Qp  = (u16*)(ws + (16ull << 20));        // [B,H,S,64]
  u16* Kp  = (u16*)(ws + (24ull << 20));        // [B,H,S,64]
  u16* Vtp = (u16*)(ws + (32ull << 20));        // [B,H,64,S]
  u16* ctx = (u16*)(ws + (40ull << 20));        // [B,S,1024]

  cast_all<<<4096, 256, 0, stream>>>(x, Wq, Wk, Wv, Wo, xb, wq, wk, wv, wo);

  // fused QKV projection: M=4096, N=3072 (grid 32 x 24, 512-thread blocks)
  gemm_qkv<<<768, 512, 0, stream>>>(xb, wq, bq, bk, bv, Qp, Kp, Vtp);

  // attention: 32 (b,h) x 16 q-tiles, 512 threads (8 waves, parallel subs)
  attn_kernel<<<512, 512, 0, stream>>>(Qp, Kp, Vtp, ctx);

  // output projection: M=4096, N=1024 (grid 32 x 16), f32 out
  gemm_o<<<512, 256, 0, stream>>>(ctx, wo, bo, (float*)d_out);
}

// Round 21
// 110.378 us; speedup vs baseline: 1.0374x; 1.0374x over previous
//
#include <hip/hip_runtime.h>
#include <hip/hip_bf16.h>

typedef unsigned short u16;
typedef unsigned int   u32;
typedef __attribute__((ext_vector_type(8)))  __bf16 bf16x8;
typedef __attribute__((ext_vector_type(4)))  float  f32x4;
typedef __attribute__((ext_vector_type(16))) float  f32x16;
typedef __attribute__((ext_vector_type(4)))  float  float4_t;
typedef __attribute__((ext_vector_type(8)))  u16    u16x8;
typedef __attribute__((ext_vector_type(4)))  u16    u16x4;
typedef __attribute__((ext_vector_type(4)))  u32    u32x4;

#define DEV static __device__ __forceinline__

// ---- helpers --------------------------------------------------------------

DEV u16 f2b(float f) {                 // f32 -> bf16 (RNE), data is finite
  u32 u = __builtin_bit_cast(u32, f);
  u32 r = u + 0x7FFFu + ((u >> 16) & 1u);
  return (u16)(r >> 16);
}

DEV u32 cvtpk(float lo, float hi) {    // pack 2 f32 -> 2 bf16 in one u32 (RNE)
  u32 r;
  asm("v_cvt_pk_bf16_f32 %0, %1, %2" : "=v"(r) : "v"(lo), "v"(hi));
  return r;
}

// bare v_exp_f32 (inputs bounded; no OCML wrapper -- R11 verified -14 us).
DEV float fexp2(float x) { return __builtin_amdgcn_exp2f(x); }

// BURIED: v_permlane32_swap_b32 (R5+R10); HBM-partial split-KV (R8); register
// squeezes (R12/R14); aligned-pack attn (R17/R18: VGPR 68/72 > 64 cliff);
// 512-thread gemm_qkv w/ 64x32 sub-tiles (R20: 1.5x LDS traffic > occupancy
// gain). INVARIANTS: (1) attn must allocate <= 64 VGPR; (2) never
// launch_bounds below natural VGPR need; (3) 64x64/wave sub-tile is the
// reuse/occupancy optimum for the 2-barrier GEMM structure.

DEV bf16x8 ldfrag(const u16* p) {      // 16B LDS vector load -> mfma operand
  u16x8 t = *(const u16x8*)p;
  return __builtin_bit_cast(bf16x8, t);
}

DEV void gload16(void* lds, const void* g) {
  // async global->LDS, 16B/lane. LDS dest = wave-uniform base + lane*16.
  __builtin_amdgcn_global_load_lds(
      (const __attribute__((address_space(1))) void*)g,
      (__attribute__((address_space(3))) void*)lds, 16, 0, 0);
}

// XOR bank swizzles (u16 offset for logical (row, col16); XOR is an involution)
DEV int swz8(int row, int col16)  { return row * 64  + ((col16 ^ (row & 7))  << 3); } // 128B rows
DEV int swz16(int row, int col16) { return row * 128 + ((col16 ^ (row & 15)) << 3); } // 256B rows

// ---- fused cast f32 -> bf16: x (4096x1024) + 4 weight matrices, one launch --

__global__ void cast_all(const float* __restrict__ x,
                         const float* __restrict__ s0, const float* __restrict__ s1,
                         const float* __restrict__ s2, const float* __restrict__ s3,
                         u16* __restrict__ xb,
                         u16* __restrict__ d0, u16* __restrict__ d1,
                         u16* __restrict__ d2, u16* __restrict__ d3) {
  const int gid = blockIdx.x * 256 + threadIdx.x;   // 4096 blocks x 256 = 1,048,576
  const float* src; u16* dst; int i;
  if (gid < 524288) { src = x; dst = xb; i = gid; }
  else {
    const int g = gid - 524288, which = g >> 17;    // 131072 vec8 per matrix
    i = g & 131071;
    src = which == 0 ? s0 : which == 1 ? s1 : which == 2 ? s2 : s3;
    dst = which == 0 ? d0 : which == 1 ? d1 : which == 2 ? d2 : d3;
  }
  float4_t a = ((const float4_t*)src)[2 * i];
  float4_t b = ((const float4_t*)src)[2 * i + 1];
  u16x8 o;
  o[0] = f2b(a[0]); o[1] = f2b(a[1]); o[2] = f2b(a[2]); o[3] = f2b(a[3]);
  o[4] = f2b(b[0]); o[5] = f2b(b[1]); o[6] = f2b(b[2]); o[7] = f2b(b[3]);
  ((u16x8*)dst)[i] = o;
}

// ---- QKV GEMM: C = A @ B^T, A[4096][1024]=x, B[3072][1024]=Wq|Wk|Wv.
// R19 VERBATIM: 128x128 tile, grid 32x24=768, (256,3), 64x64/wave sub-tiles.
// T2 XOR-swizzle on As/Bs (R15 win); V packed 8B stores (R18 win).

__global__ __launch_bounds__(256, 3) void gemm_qkv(
    const u16* __restrict__ A, const u16* __restrict__ Bm,
    const float* __restrict__ bq, const float* __restrict__ bk, const float* __restrict__ bv,
    u16* __restrict__ oQ, u16* __restrict__ oK, u16* __restrict__ oV)
{
  __shared__ u16 As[128 * 64];
  __shared__ u16 Bs[128 * 64];
  const int t = threadIdx.x, w = t >> 6, ln = t & 63;
  const int bm = blockIdx.x & 31, bn = blockIdx.x >> 5;
  const int m0 = bm * 128, n0 = bn * 128;
  const int wm = (w >> 1) * 64, wn = (w & 1) * 64;
  const int srow = ln >> 3;
  const int scolx = ((ln & 7) ^ (ln >> 3)) << 3;   // pre-swizzled source col (u16)

  f32x4 acc[4][4] = {};

  for (int k0 = 0; k0 < 1024; k0 += 64) {
#pragma unroll
    for (int i = 0; i < 4; ++i) {
      const int c = w * 4 + i;                     // chunk 0..15 (8 rows each)
      gload16(&As[c * 512], A  + (size_t)(m0 + c * 8 + srow) * 1024 + k0 + scolx);
      gload16(&Bs[c * 512], Bm + (size_t)(n0 + c * 8 + srow) * 1024 + k0 + scolx);
    }
    __syncthreads();
#pragma unroll
    for (int kh = 0; kh < 2; ++kh) {
      bf16x8 af[4], bf[4];
#pragma unroll
      for (int i = 0; i < 4; ++i)
        af[i] = ldfrag(&As[swz8(wm + i * 16 + (ln & 15), kh * 4 + (ln >> 4))]);
#pragma unroll
      for (int j = 0; j < 4; ++j)
        bf[j] = ldfrag(&Bs[swz8(wn + j * 16 + (ln & 15), kh * 4 + (ln >> 4))]);
#pragma unroll
      for (int i = 0; i < 4; ++i)
#pragma unroll
        for (int j = 0; j < 4; ++j)
          acc[i][j] = __builtin_amdgcn_mfma_f32_16x16x32_bf16(af[i], bf[j], acc[i][j], 0, 0, 0);
    }
    __syncthreads();
  }

  // epilogue: D mapping col=lane&15, row=(lane>>4)*4+reg  [verified m89/m91]
#pragma unroll
  for (int i = 0; i < 4; ++i) {
#pragma unroll
    for (int j = 0; j < 4; ++j) {
      const int col = n0 + wn + j * 16 + (ln & 15);
      const int p = col >> 10, nn = col & 1023;         // uniform per block
      const int h = nn >> 6, d = nn & 63;
      if (p == 2) {
        // V: lane owns 4 consecutive s for fixed d -> one packed 8B store
        const int row0 = m0 + wm + i * 16 + (ln >> 4) * 4;
        const int b = row0 >> 11, sv = row0 & 2047;
        u16x4 pk;
#pragma unroll
        for (int r = 0; r < 4; ++r) pk[r] = f2b(acc[i][j][r] + bv[nn]);
        *(u16x4*)&oV[((size_t)((b * 16 + h) * 64 + d) << 11) + sv] = pk;
      } else {
#pragma unroll
        for (int r = 0; r < 4; ++r) {
          const int row = m0 + wm + i * 16 + (ln >> 4) * 4 + r;
          const int b = row >> 11, s = row & 2047;
          const float v = acc[i][j][r];
          const size_t qk = ((size_t)((b * 16 + h) * 2048 + s) << 6) + d;
          if (p == 0) oQ[qk] = f2b((v + bq[nn]) * 0.18033688f);  // 1/8 * log2(e)
          else        oK[qk] = f2b(v + bk[nn]);
        }
      }
    }
  }
}

// ---- output GEMM: out = ctx @ Wo^T + bo, f32 out. 128x64 tile, grid 512. ----

__global__ __launch_bounds__(256, 2) void gemm_o(
    const u16* __restrict__ A, const u16* __restrict__ Bm,
    const float* __restrict__ bias, float* __restrict__ oF)
{
  __shared__ u16 As[128 * 64];
  __shared__ u16 Bs[64 * 64];
  const int t = threadIdx.x, w = t >> 6, ln = t & 63;
  const int bm = blockIdx.x & 31, bn = blockIdx.x >> 5;   // 32 x 16
  const int m0 = bm * 128, n0 = bn * 64;
  const int wm = (w >> 1) * 64, wn = (w & 1) * 32;
  const int srow = ln >> 3;
  const int scolx = ((ln & 7) ^ (ln >> 3)) << 3;   // pre-swizzled source col (u16)

  f32x4 acc[4][2] = {};

  for (int k0 = 0; k0 < 1024; k0 += 64) {
#pragma unroll
    for (int i = 0; i < 4; ++i) {
      const int c = w * 4 + i;                     // A chunks 0..15
      gload16(&As[c * 512], A + (size_t)(m0 + c * 8 + srow) * 1024 + k0 + scolx);
    }
#pragma unroll
    for (int i = 0; i < 2; ++i) {
      const int c = w * 2 + i;                     // B chunks 0..7
      gload16(&Bs[c * 512], Bm + (size_t)(n0 + c * 8 + srow) * 1024 + k0 + scolx);
    }
    __syncthreads();
#pragma unroll
    for (int kh = 0; kh < 2; ++kh) {
      bf16x8 af[4], bf[2];
#pragma unroll
      for (int i = 0; i < 4; ++i)
        af[i] = ldfrag(&As[swz8(wm + i * 16 + (ln & 15), kh * 4 + (ln >> 4))]);
#pragma unroll
      for (int j = 0; j < 2; ++j)
        bf[j] = ldfrag(&Bs[swz8(wn + j * 16 + (ln & 15), kh * 4 + (ln >> 4))]);
#pragma unroll
      for (int i = 0; i < 4; ++i)
#pragma unroll
        for (int j = 0; j < 2; ++j)
          acc[i][j] = __builtin_amdgcn_mfma_f32_16x16x32_bf16(af[i], bf[j], acc[i][j], 0, 0, 0);
    }
    __syncthreads();
  }

#pragma unroll
  for (int i = 0; i < 4; ++i) {
#pragma unroll
    for (int j = 0; j < 2; ++j) {
      const int col = n0 + wn + j * 16 + (ln & 15);
#pragma unroll
      for (int r = 0; r < 4; ++r) {
        const int row = m0 + wm + i * 16 + (ln >> 4) * 4 + r;
        oF[(size_t)row * 1024 + col] = acc[i][j][r] + bias[col];
      }
    }
  }
}

// ---- flash attention: R16/R19 VERBATIM (47.5 us, 64 VGPR, 35% occupancy) ----
// 512 thr = 8 waves (qgrp=w&3 x g=w>>2 kv half), dbuf KV, issue-first
// prefetch, XCD-local bh, max-free softmax, (512,2), cross-hi exchange via
// shfl_xor+cndmask (verified R4/R6), LDS combine of the two kv halves.

__global__ __launch_bounds__(512, 2) void attn_kernel(
    const u16* __restrict__ Qg, const u16* __restrict__ Kg,
    const u16* __restrict__ Vtg, u16* __restrict__ Ctx)
{
  __shared__ u16 Kb[2][128 * 64];  // K tiles (Q staged in Kb[1] once); swz8
  __shared__ u16 Vb[2][64 * 128];  // V^T tiles [d][kv]; swz16

  const int t = threadIdx.x, w = t >> 6, ln = t & 63;
  const int lo5 = ln & 31, hi = ln >> 5;
  const int qgrp = w & 3;          // 32-q-row group within the 128-row block
  const int g = w >> 2;            // kv half of each 128-tile (0: [0,64), 1: [64,128))
  const int bh = blockIdx.x & 31;           // 0..31 = b*16+h (same-head -> same XCD)
  const int q0 = (blockIdx.x >> 5) * 128;
  const size_t base = (size_t)bh << 17;     // bh*2048*64

  auto stageKV = [&](int buf, int kv0) {
#pragma unroll
    for (int i = 0; i < 2; ++i) {
      const int c = w * 2 + i;               // chunks 0..15 across 8 waves
      gload16(&Kb[buf][c * 512],
              Kg + base + (size_t)(kv0 + c * 8 + (ln >> 3)) * 64 + (((ln & 7) ^ (ln >> 3)) << 3));
      const int vr = c * 4 + (ln >> 4);      // V^T row (d)
      gload16(&Vb[buf][c * 512],
              Vtg + base + (size_t)vr * 2048 + kv0 + (((ln & 15) ^ (vr & 15)) << 3));
    }
  };

  // stage Q tile [128][64] into Kb[1] (pre-swizzled source, linear LDS dest)
#pragma unroll
  for (int i = 0; i < 2; ++i) {
    const int c = w * 2 + i;
    gload16(&Kb[1][c * 512],
            Qg + base + (size_t)(q0 + c * 8 + (ln >> 3)) * 64 + (((ln & 7) ^ (ln >> 3)) << 3));
  }
  __syncthreads();

  stageKV(0, 0);                   // K0/V0 in flight while we read Q fragments

  // Q B-fragments: col=q=lo5, k(d) = kh*16 + hi*8 + j
  bf16x8 qf[4];
#pragma unroll
  for (int kh = 0; kh < 4; ++kh)
    qf[kh] = ldfrag(&Kb[1][swz8(qgrp * 32 + lo5, 2 * kh + hi)]);
  __syncthreads();                 // drains K0/V0; all waves read Q before kt=0 hits Kb[1]

  f32x16 acc[2] = {};              // O[q][d]: db=0,1; row=(rg&3)+8*(rg>>2)+4*hi, col=db*32+lo5
  float l_i = 0.f;                 // softmax denominator for this wave's kv half

#pragma unroll 2
  for (int kt = 0; kt < 16; ++kt) {
    const int cur = kt & 1;
    if (kt < 15) stageKV(cur ^ 1, (kt + 1) * 128);   // issue-first prefetch
    const u16* KQs = Kb[cur];
    const u16* Vs  = Vb[cur];

    // ---- S^T = K Q^T over this wave's 64-kv half (g)
    f32x16 S0 = {}, S1 = {};
    __builtin_amdgcn_s_setprio(1);
#pragma unroll
    for (int kh = 0; kh < 4; ++kh) {
      bf16x8 a0 = ldfrag(&KQs[swz8(g * 64 + lo5,      2 * kh + hi)]);
      bf16x8 a1 = ldfrag(&KQs[swz8(g * 64 + 32 + lo5, 2 * kh + hi)]);
      S0 = __builtin_amdgcn_mfma_f32_32x32x16_bf16(a0, qf[kh], S0, 0, 0, 0);
      S1 = __builtin_amdgcn_mfma_f32_32x32x16_bf16(a1, qf[kh], S1, 0, 0, 0);
    }
    __builtin_amdgcn_s_setprio(0);

    // ---- P = exp2(S) directly (max-free), row sum via 4 partial accumulators
    float s0 = 0.f, s1 = 0.f, s2 = 0.f, s3 = 0.f;
#pragma unroll
    for (int r = 0; r < 16; r += 4) {
      S0[r]     = fexp2(S0[r]);     s0 += S0[r];
      S0[r + 1] = fexp2(S0[r + 1]); s1 += S0[r + 1];
      S0[r + 2] = fexp2(S0[r + 2]); s2 += S0[r + 2];
      S0[r + 3] = fexp2(S0[r + 3]); s3 += S0[r + 3];
    }
#pragma unroll
    for (int r = 0; r < 16; r += 4) {
      S1[r]     = fexp2(S1[r]);     s0 += S1[r];
      S1[r + 1] = fexp2(S1[r + 1]); s1 += S1[r + 1];
      S1[r + 2] = fexp2(S1[r + 2]); s2 += S1[r + 2];
      S1[r + 3] = fexp2(S1[r + 3]); s3 += S1[r + 3];
    }
    float sum = (s0 + s1) + (s2 + s3);
    sum += __shfl_xor(sum, 32);
    l_i += sum;

    // ---- pack P -> u32 words per kv-4-block (own parity blocks n = 2u + hi)
    u32 w2[8][2];
#pragma unroll
    for (int u = 0; u < 8; ++u) {
      const int tt = u & 3;
      if (u < 4) {
        w2[u][0] = cvtpk(S0[4 * tt + 0], S0[4 * tt + 1]);
        w2[u][1] = cvtpk(S0[4 * tt + 2], S0[4 * tt + 3]);
      } else {
        w2[u][0] = cvtpk(S1[4 * tt + 0], S1[4 * tt + 1]);
        w2[u][1] = cvtpk(S1[4 * tt + 2], S1[4 * tt + 3]);
      }
    }

    // ---- PV: A-frag pa[m] = P[q][kv=16m+8hi+j]; exchange odd/even blocks across hi.
    // All w2 indices STATIC; hi-dependent selection via v_cndmask on values.
    __builtin_amdgcn_s_setprio(1);
#pragma unroll
    for (int m = 0; m < 4; ++m) {
      const u32 a0 = w2[2 * m][0],     a1 = w2[2 * m][1];      // even-parity block
      const u32 b0 = w2[2 * m + 1][0], b1 = w2[2 * m + 1][1];  // odd-parity block
      const u32 o0 = hi ? b0 : a0,     o1 = hi ? b1 : a1;      // own block
      const u32 x0 = hi ? a0 : b0,     x1 = hi ? a1 : b1;      // sent to partner
      const u32 r0 = (u32)__shfl_xor((int)x0, 32);
      const u32 r1 = (u32)__shfl_xor((int)x1, 32);
      u32x4 fw;
      fw[0] = hi ? r0 : o0;   // block 4m+2hi   (kv 16m+8hi .. +3)
      fw[1] = hi ? r1 : o1;
      fw[2] = hi ? o0 : r0;   // block 4m+2hi+1 (kv 16m+8hi+4 .. +7)
      fw[3] = hi ? o1 : r1;
      const bf16x8 pa = __builtin_bit_cast(bf16x8, fw);
      const bf16x8 v0 = ldfrag(&Vs[swz16(lo5,      g * 8 + 2 * m + hi)]);
      const bf16x8 v1 = ldfrag(&Vs[swz16(32 + lo5, g * 8 + 2 * m + hi)]);
      acc[0] = __builtin_amdgcn_mfma_f32_32x32x16_bf16(pa, v0, acc[0], 0, 0, 0);
      acc[1] = __builtin_amdgcn_mfma_f32_32x32x16_bf16(pa, v1, acc[1], 0, 0, 0);
    }
    __builtin_amdgcn_s_setprio(0);

    __syncthreads();   // drains stage(kt+1); LDS handoff for next tile
  }

  // ---- combine the two kv halves (max-free: plain adds), reuse Kb/Vb as f32
  float* Lo  = (float*)&Kb[0][0];          // [4 qgrp][32 row][64 col] f32 = 32 KB
  float* Lml = (float*)&Vb[0][0];          // [4 qgrp][32 q] l partials (512 B)
  if (g == 1) {
    if (hi == 0) Lml[qgrp * 32 + lo5] = l_i;
#pragma unroll
    for (int rg = 0; rg < 16; ++rg) {
      const int row = (rg & 3) + 8 * (rg >> 2) + 4 * hi;
#pragma unroll
      for (int db = 0; db < 2; ++db)
        Lo[(qgrp * 32 + row) * 64 + db * 32 + lo5] = acc[db][rg];
    }
  }
  __syncthreads();

  if (g == 0) {                            // merge + normalize + write ctx
    const float linv = 1.f / (l_i + Lml[qgrp * 32 + lo5]);
    const int b = bh >> 4, h = bh & 15;
#pragma unroll
    for (int rg = 0; rg < 16; ++rg) {
      const int qrow = (rg & 3) + 8 * (rg >> 2) + 4 * hi;
      const float li = __shfl(linv, qrow);
      const int s = q0 + qgrp * 32 + qrow;
#pragma unroll
      for (int db = 0; db < 2; ++db) {
        const int d = db * 32 + lo5;
        const float oB = Lo[(qgrp * 32 + qrow) * 64 + d];
        Ctx[((size_t)(b * 2048 + s) << 10) + h * 64 + d] = f2b((acc[db][rg] + oB) * li);
      }
    }
  }
}

// ---- launch ----------------------------------------------------------------

extern "C" void kernel_launch(void* const* d_in, const int* in_sizes, int n_in,
                              void* d_out, int out_size, void* d_ws, size_t ws_size,
                              hipStream_t stream) {
  const float* x  = (const float*)d_in[0];
  const float* Wq = (const float*)d_in[2];
  const float* bq = (const float*)d_in[3];
  const float* Wk = (const float*)d_in[4];
  const float* bk = (const float*)d_in[5];
  const float* Wv = (const float*)d_in[6];
  const float* bv = (const float*)d_in[7];
  const float* Wo = (const float*)d_in[8];
  const float* bo = (const float*)d_in[9];

  char* ws = (char*)d_ws;
  // workspace layout (48 MB total), all offsets 2MB-aligned
  u16* xb  = (u16*)(ws);                        // x bf16 [4096][1024]
  u16* wq  = (u16*)(ws + (8ull  << 20));        // Wq|Wk|Wv contiguous [3072][1024]
  u16* wk  = (u16*)(ws + (10ull << 20));
  u16* wv  = (u16*)(ws + (12ull << 20));
  u16* wo  = (u16*)(ws + (14ull << 20));        // Wo [1024][1024]
  u16* Qp  = (u16*)(ws + (16ull << 20));        // [B,H,S,64]
  u16* Kp  = (u16*)(ws + (24ull << 20));        // [B,H,S,64]
  u16* Vtp = (u16*)(ws + (32ull << 20));        // [B,H,64,S]
  u16* ctx = (u16*)(ws + (40ull << 20));        // [B,S,1024]

  cast_all<<<4096, 256, 0, stream>>>(x, Wq, Wk, Wv, Wo, xb, wq, wk, wv, wo);

  // fused QKV projection: M=4096, N=3072 (grid 32 x 24, 128x128 tiles, 3/CU)
  gemm_qkv<<<768, 256, 0, stream>>>(xb, wq, bq, bk, bv, Qp, Kp, Vtp);

  // attention: 32 (b,h) x 16 q-tiles, 512 threads (8 waves, parallel subs)
  attn_kernel<<<512, 512, 0, stream>>>(Qp, Kp, Vtp, ctx);

  // output projection: M=4096, N=1024 (grid 32 x 16), f32 out
  gemm_o<<<512, 256, 0, stream>>>(ctx, wo, bo, (float*)d_out);
}